// Round 16
// baseline (189.588 us; speedup 1.0000x reference)
//
#include <hip/hip_runtime.h>
#include <hip/hip_bf16.h>
#include <math.h>

#define DIN 256
#define EDIM 16
#define HC 128          // H*C
#define GBM 64          // GEMM tile M
#define GBN 256         // GEMM tile N (Wl cols | Wr cols)
#define GBK 32          // GEMM K step
#define LDS_STRIDE 40   // padded LDS row stride in shorts
#define BSTRIDE 64      // bucket slots per node (Poisson(16): P(deg>64) ~ 1e-20)

typedef __attribute__((ext_vector_type(8))) short short8v;
typedef __attribute__((ext_vector_type(4))) float floatx4;
typedef __attribute__((ext_vector_type(2))) float floatx2;
typedef __attribute__((ext_vector_type(4))) unsigned short ushort4v;
typedef __attribute__((ext_vector_type(2))) int intx2;

__device__ inline unsigned short f2bf(float f) {
    union { float f; unsigned u; } v; v.f = f;
    unsigned r = v.u + 0x7FFF + ((v.u >> 16) & 1);   // RNE
    return (unsigned short)(r >> 16);
}

// 32-lane sum within each half-wave, result broadcast to all lanes.
__device__ inline float rsum32(float v) {
    int x;
    x = __builtin_amdgcn_update_dpp(0, __builtin_bit_cast(int, v), 0xB1, 0xF, 0xF, true);  // quad_perm [1,0,3,2]
    v += __builtin_bit_cast(float, x);
    x = __builtin_amdgcn_update_dpp(0, __builtin_bit_cast(int, v), 0x4E, 0xF, 0xF, true);  // quad_perm [2,3,0,1]
    v += __builtin_bit_cast(float, x);
    x = __builtin_amdgcn_update_dpp(0, __builtin_bit_cast(int, v), 0x124, 0xF, 0xF, true); // row_ror:4
    v += __builtin_bit_cast(float, x);
    x = __builtin_amdgcn_update_dpp(0, __builtin_bit_cast(int, v), 0x128, 0xF, 0xF, true); // row_ror:8
    v += __builtin_bit_cast(float, x);
    v += __builtin_bit_cast(float, __builtin_amdgcn_ds_swizzle(__builtin_bit_cast(int, v), 0x401F)); // xor 16
    return v;
}

// ---------------- setup: cnt=0 | Wc,bc | Wb (all independent) ----------------
__global__ __launch_bounds__(256) void k_setup(const float* __restrict__ W_ep,
    const float* __restrict__ b_ep, const float* __restrict__ W_e,
    const float* __restrict__ Wl, const float* __restrict__ Wr,
    float* __restrict__ Wc, float* __restrict__ bc,
    unsigned short* __restrict__ Wb, int* __restrict__ cnt, int n) {
    const int NB_W = (GBN / 32) * (DIN / 32);       // 64
    int b = blockIdx.x;
    if (b < NB_W) {
        __shared__ unsigned short tile[32][33];
        int bx = b & 7, by = b >> 3;                // bx: col tile, by: k tile
        int tx = threadIdx.x & 31, ty = threadIdx.x >> 5;
        int c0 = bx * 32, k0 = by * 32;
#pragma unroll
        for (int i = 0; i < 4; ++i) {
            int k = k0 + ty + i * 8;
            int col = c0 + tx;
            float v = (col < HC) ? Wl[(size_t)k * HC + col] : Wr[(size_t)k * HC + (col - HC)];
            tile[ty + i * 8][tx] = f2bf(v);
        }
        __syncthreads();
#pragma unroll
        for (int i = 0; i < 4; ++i) {
            int col = c0 + ty + i * 8;
            int k = k0 + tx;
            Wb[(size_t)col * DIN + k] = tile[tx][ty + i * 8];
        }
    } else if (b < NB_W + 9) {
        int tid = (b - NB_W) * 256 + threadIdx.x;
        if (tid < EDIM * HC) {
            int k = tid >> 7, j = tid & 127;
            float s = 0.f;
            for (int d = 0; d < DIN; ++d) s += W_ep[k * DIN + d] * W_e[d * HC + j];
            Wc[tid] = s;
        } else if (tid < EDIM * HC + HC) {
            int j = tid - EDIM * HC;
            float s = 0.f;
            for (int d = 0; d < DIN; ++d) s += b_ep[d] * W_e[d * HC + j];
            bc[j] = s;
        }
    } else {
        int i = (b - NB_W - 9) * 256 + threadIdx.x;
        if (i < n) cnt[i] = 0;
    }
}

// ---------------- fused: MFMA GEMM (first) + bucket scatter -------------------
__global__ __launch_bounds__(256) void k_mmsc(const float* __restrict__ x,
    const unsigned short* __restrict__ Wb,
    const float* __restrict__ bl, const float* __restrict__ br,
    unsigned* __restrict__ xlq, float* __restrict__ xrp,
    const int* __restrict__ ei, int* __restrict__ cnt,
    intx2* __restrict__ buckets, int M, int E, int MMB) {
    __shared__ unsigned short As[GBM * LDS_STRIDE];
    __shared__ unsigned short Bs[GBN * LDS_STRIDE];

    int t = threadIdx.x;
    if ((int)blockIdx.x >= MMB) {
        int e = (blockIdx.x - MMB) * 256 + t;
        if (e < E) {
            int dst = ei[E + e];
            int pos = atomicAdd(&cnt[dst], 1);
            if (pos < BSTRIDE) {
                intx2 se; se.x = ei[e]; se.y = e;
                buckets[(size_t)dst * BSTRIDE + pos] = se;
            }
        }
        return;
    }

    int wid = t >> 6, lane = t & 63;
    int m0 = blockIdx.x * GBM;

    floatx4 acc[4][4];
#pragma unroll
    for (int i = 0; i < 4; ++i)
#pragma unroll
        for (int j = 0; j < 4; ++j) acc[i][j] = (floatx4){0.f, 0.f, 0.f, 0.f};

    int row_l = lane & 15, kg = (lane >> 4) * 8;

    for (int kb = 0; kb < DIN; kb += GBK) {
        {   // stage A: 64 rows x 32 fp32 -> bf16
            int r = t >> 2, kk = (t & 3) * 8;
            int gr = m0 + r; if (gr >= M) gr = M - 1;
            const float* xp = x + (size_t)gr * DIN + kb + kk;
            floatx4 v0 = *(const floatx4*)xp;
            floatx4 v1 = *(const floatx4*)(xp + 4);
            ushort4v u0, u1;
            u0[0] = f2bf(v0[0]); u0[1] = f2bf(v0[1]); u0[2] = f2bf(v0[2]); u0[3] = f2bf(v0[3]);
            u1[0] = f2bf(v1[0]); u1[1] = f2bf(v1[1]); u1[2] = f2bf(v1[2]); u1[3] = f2bf(v1[3]);
            *(ushort4v*)(&As[r * LDS_STRIDE + kk]) = u0;
            *(ushort4v*)(&As[r * LDS_STRIDE + kk + 4]) = u1;
        }
#pragma unroll
        for (int j = 0; j < 4; ++j) {          // stage B: 256 cols x 32 bf16
            int c = t + 256 * j;
            int col = c >> 2, kk = (c & 3) * 8;
            short8v v = *(const short8v*)(Wb + (size_t)col * DIN + kb + kk);
            *(short8v*)(&Bs[col * LDS_STRIDE + kk]) = v;
        }
        __syncthreads();

        short8v a[4], b[4];
#pragma unroll
        for (int i = 0; i < 4; ++i)
            a[i] = *(short8v*)(&As[(i * 16 + row_l) * LDS_STRIDE + kg]);
#pragma unroll
        for (int j = 0; j < 4; ++j)
            b[j] = *(short8v*)(&Bs[(wid * 64 + j * 16 + row_l) * LDS_STRIDE + kg]);
#pragma unroll
        for (int i = 0; i < 4; ++i)
#pragma unroll
            for (int j = 0; j < 4; ++j)
                acc[i][j] = __builtin_amdgcn_mfma_f32_16x16x32_bf16(a[i], b[j], acc[i][j], 0, 0, 0);
        __syncthreads();
    }

    int colf = lane & 15, rq = (lane >> 4) * 4;
    if (wid < 2) {
        // xl half: packed bf16x2, one u32 per (row, l) -> coalesced
#pragma unroll
        for (int j = 0; j < 2; ++j) {
            int col = wid * 64 + j * 16 + colf;
            float bs_lo = bl[col], bs_hi = bl[col + 32];
            int l = wid * 32 + j * 16 + colf;
#pragma unroll
            for (int i = 0; i < 4; ++i) {
#pragma unroll
                for (int q = 0; q < 4; ++q) {
                    int row = m0 + i * 16 + rq + q;
                    if (row < M) {
                        unsigned lo = f2bf(acc[i][j][q] + bs_lo);
                        unsigned hi = f2bf(acc[i][j + 2][q] + bs_hi);
                        xlq[(size_t)row * 64 + l] = lo | (hi << 16);
                    }
                }
            }
        }
    } else {
        // xr half: full float2 per (row, l) -> no write amplification
#pragma unroll
        for (int j = 0; j < 2; ++j) {
            int col = wid * 64 + j * 16 + colf;
            int pc = col - HC;
            float bs_lo = br[pc], bs_hi = br[pc + 32];
            int l = (pc >> 6) * 32 + (pc & 31);
#pragma unroll
            for (int i = 0; i < 4; ++i) {
#pragma unroll
                for (int q = 0; q < 4; ++q) {
                    int row = m0 + i * 16 + rq + q;
                    if (row < M) {
                        floatx2 v;
                        v.x = acc[i][j][q] + bs_lo;
                        v.y = acc[i][j + 2][q] + bs_hi;
                        *(floatx2*)(xrp + ((size_t)row * 64 + l) * 2) = v;
                    }
                }
            }
        }
    }
}

// ---------------- fused per-node attention + aggregation ----------------------
// 128 threads = 2 waves = 2 nodes; half-wave per head; lane owns 2 ch.
// Unroll-8: 8 gathers + 8 ea streams in flight per iteration (deg~16 -> 2 iters),
// folding into 4 independent accumulator chains.
__global__ __launch_bounds__(128, 4) void k_node(const unsigned* __restrict__ xlq,
    const float* __restrict__ xrp, const float* __restrict__ Wc,
    const float* __restrict__ bc, const float* __restrict__ att,
    const float* __restrict__ bias, const int* __restrict__ cnt,
    const intx2* __restrict__ buckets,
    const float* __restrict__ edge_attr, float* __restrict__ out, int n) {
    int wid = __builtin_amdgcn_readfirstlane(threadIdx.x >> 6);
    int lane = threadIdx.x & 63;
    int node = blockIdx.x * 2 + wid;
    if (node >= n) return;
    int g = lane >> 5;
    int ch_a = g * 64 + (lane & 31);
    int ch_b = ch_a + 32;

    floatx2 wc2[EDIM];
#pragma unroll
    for (int k = 0; k < EDIM; ++k) {
        wc2[k].x = Wc[k * HC + ch_a];
        wc2[k].y = Wc[k * HC + ch_b];
    }
    const float L2E = 1.44269504f;
    floatx2 att2; att2.x = att[ch_a] * L2E; att2.y = att[ch_b] * L2E;
    floatx2 xr2 = *(const floatx2*)(xrp + ((size_t)node * 64 + lane) * 2);
    floatx2 base2; base2.x = bc[ch_a] + xr2.x; base2.y = bc[ch_b] + xr2.y;

    int deg = cnt[node]; if (deg > BSTRIDE) deg = BSTRIDE;
    const intx2* __restrict__ bk = buckets + (size_t)node * BSTRIDE;

    // prefetch bucket entries: lane p holds entry p (deg <= 64)
    int bsrc = 0, beid = 0;
    if (lane < deg) {
        intx2 se = bk[lane];
        bsrc = se.x; beid = se.y;
    }

    float D0 = 0.f, D1 = 0.f, D2 = 0.f, D3 = 0.f;
    floatx2 z; z.x = 0.f; z.y = 0.f;
    floatx2 acc0 = z, acc1 = z, acc2 = z, acc3 = z;

    for (int p = 0; p < deg; p += 8) {
        int s0 = __builtin_amdgcn_readlane(bsrc, p);
        int e0 = __builtin_amdgcn_readlane(beid, p);
        int s1 = __builtin_amdgcn_readlane(bsrc, p + 1);
        int e1 = __builtin_amdgcn_readlane(beid, p + 1);
        int s2 = __builtin_amdgcn_readlane(bsrc, p + 2);
        int e2 = __builtin_amdgcn_readlane(beid, p + 2);
        int s3 = __builtin_amdgcn_readlane(bsrc, p + 3);
        int e3 = __builtin_amdgcn_readlane(beid, p + 3);
        int s4 = __builtin_amdgcn_readlane(bsrc, p + 4);
        int e4 = __builtin_amdgcn_readlane(beid, p + 4);
        int s5 = __builtin_amdgcn_readlane(bsrc, p + 5);
        int e5 = __builtin_amdgcn_readlane(beid, p + 5);
        int s6 = __builtin_amdgcn_readlane(bsrc, p + 6);
        int e6 = __builtin_amdgcn_readlane(beid, p + 6);
        int s7 = __builtin_amdgcn_readlane(bsrc, p + 7);
        int e7 = __builtin_amdgcn_readlane(beid, p + 7);
        // all 8 gathers in flight
        unsigned v0 = xlq[(size_t)s0 * 64 + lane];
        unsigned v1 = xlq[(size_t)s1 * 64 + lane];
        unsigned v2 = xlq[(size_t)s2 * 64 + lane];
        unsigned v3 = xlq[(size_t)s3 * 64 + lane];
        unsigned v4 = xlq[(size_t)s4 * 64 + lane];
        unsigned v5 = xlq[(size_t)s5 * 64 + lane];
        unsigned v6 = xlq[(size_t)s6 * 64 + lane];
        unsigned v7 = xlq[(size_t)s7 * 64 + lane];

#define SLOT(K, vv, ee_id, Dk, acck)                                              \
        {                                                                          \
            const floatx4* __restrict__ ea = (const floatx4*)(edge_attr + (size_t)(ee_id) * EDIM); \
            floatx2 ee = base2;                                                    \
            _Pragma("unroll")                                                      \
            for (int q = 0; q < 4; ++q) {                                          \
                floatx4 av = ea[q];                                                \
                _Pragma("unroll")                                                  \
                for (int k = 0; k < 4; ++k) ee += av[k] * wc2[q * 4 + k];          \
            }                                                                      \
            floatx2 xl2;                                                           \
            xl2.x = __builtin_bit_cast(float, (vv) << 16);                         \
            xl2.y = __builtin_bit_cast(float, (vv) & 0xFFFF0000u);                 \
            floatx2 m = xl2 + ee;                                                  \
            floatx2 lr;                                                            \
            lr.x = fmaxf(m.x, 0.f) + 0.2f * fminf(m.x, 0.f);                       \
            lr.y = fmaxf(m.y, 0.f) + 0.2f * fminf(m.y, 0.f);                       \
            float sc = lr.x * att2.x + lr.y * att2.y;                              \
            sc = rsum32(sc);                                                       \
            float w = (p + (K) < deg) ? exp2f(sc) : 0.f;                           \
            Dk += w;                                                               \
            acck += w * xl2;                                                       \
        }

        SLOT(0, v0, e0, D0, acc0)
        SLOT(1, v1, e1, D1, acc1)
        SLOT(2, v2, e2, D2, acc2)
        SLOT(3, v3, e3, D3, acc3)
        SLOT(4, v4, e4, D0, acc0)
        SLOT(5, v5, e5, D1, acc1)
        SLOT(6, v6, e6, D2, acc2)
        SLOT(7, v7, e7, D3, acc3)
#undef SLOT
    }

    float D = (D0 + D1) + (D2 + D3);
    floatx2 acc = (acc0 + acc1) + (acc2 + acc3);
    float invD = (D > 0.f) ? 1.f / D : 0.f;
    out[(size_t)node * HC + ch_a] = acc.x * invD + bias[ch_a];
    out[(size_t)node * HC + ch_b] = acc.y * invD + bias[ch_b];
}

// -----------------------------------------------------------------------------
extern "C" void kernel_launch(void* const* d_in, const int* in_sizes, int n_in,
                              void* d_out, int out_size, void* d_ws, size_t ws_size,
                              hipStream_t stream) {
    const float* x    = (const float*)d_in[0];
    const int*   ei   = (const int*)d_in[1];
    const float* eatt = (const float*)d_in[2];
    const float* W_ep = (const float*)d_in[3];
    const float* b_ep = (const float*)d_in[4];
    const float* W_l  = (const float*)d_in[5];
    const float* b_l  = (const float*)d_in[6];
    const float* W_r  = (const float*)d_in[7];
    const float* b_r  = (const float*)d_in[8];
    const float* W_e  = (const float*)d_in[9];
    const float* att  = (const float*)d_in[10];
    const float* bias = (const float*)d_in[11];
    float* out = (float*)d_out;

    const int N = in_sizes[0] / DIN;
    const int E = in_sizes[1] / 2;

    char* w = (char*)d_ws;
    size_t o = 0;
    auto alloc = [&](size_t bytes) {
        o = (o + 255) & ~(size_t)255;
        void* p = w + o;
        o += bytes;
        return p;
    };
    unsigned* xlq      = (unsigned*)alloc((size_t)N * 64 * sizeof(unsigned));
    float* xrp         = (float*)alloc((size_t)N * HC * sizeof(float));
    intx2* buckets     = (intx2*)alloc((size_t)N * BSTRIDE * sizeof(intx2));
    unsigned short* Wb = (unsigned short*)alloc((size_t)GBN * DIN * sizeof(unsigned short));
    float* Wc          = (float*)alloc(EDIM * HC * sizeof(float));
    float* bc          = (float*)alloc(HC * sizeof(float));
    int*   cnt         = (int*)alloc((size_t)N * sizeof(int));

    const int NB_W = (GBN / 32) * (DIN / 32);                 // 64
    int setup_blocks = NB_W + 9 + (N + 255) / 256;
    k_setup<<<setup_blocks, 256, 0, stream>>>(W_ep, b_ep, W_e, W_l, W_r,
                                              Wc, bc, Wb, cnt, N);

    int MMB = (N + GBM - 1) / GBM;
    int SCB = (E + 255) / 256;
    k_mmsc<<<MMB + SCB, 256, 0, stream>>>(x, Wb, b_l, b_r, xlq, xrp,
                                          ei, cnt, buckets, N, E, MMB);

    k_node<<<(N + 1) / 2, 128, 0, stream>>>(xlq, xrp, Wc, bc, att, bias, cnt, buckets,
                                            eatt, out, N);
}

// Round 17
// 175.305 us; speedup vs baseline: 1.0815x; 1.0815x over previous
//
#include <hip/hip_runtime.h>
#include <hip/hip_bf16.h>
#include <math.h>

#define DIN 256
#define EDIM 16
#define HC 128          // H*C
#define GBM 64          // GEMM tile M
#define GBN 256         // GEMM tile N (Wl cols | Wr cols)
#define GBK 32          // GEMM K step
#define LDS_STRIDE 40   // padded LDS row stride in shorts
#define BSTRIDE 64      // bucket slots per node (Poisson(16): P(deg>64) ~ 1e-20)

typedef __attribute__((ext_vector_type(8))) short short8v;
typedef __attribute__((ext_vector_type(4))) float floatx4;
typedef __attribute__((ext_vector_type(2))) float floatx2;
typedef __attribute__((ext_vector_type(4))) unsigned short ushort4v;
typedef __attribute__((ext_vector_type(2))) int intx2;

__device__ inline unsigned short f2bf(float f) {
    union { float f; unsigned u; } v; v.f = f;
    unsigned r = v.u + 0x7FFF + ((v.u >> 16) & 1);   // RNE
    return (unsigned short)(r >> 16);
}

// 32-lane sum within each half-wave, result broadcast to all lanes.
__device__ inline float rsum32(float v) {
    int x;
    x = __builtin_amdgcn_update_dpp(0, __builtin_bit_cast(int, v), 0xB1, 0xF, 0xF, true);  // quad_perm [1,0,3,2]
    v += __builtin_bit_cast(float, x);
    x = __builtin_amdgcn_update_dpp(0, __builtin_bit_cast(int, v), 0x4E, 0xF, 0xF, true);  // quad_perm [2,3,0,1]
    v += __builtin_bit_cast(float, x);
    x = __builtin_amdgcn_update_dpp(0, __builtin_bit_cast(int, v), 0x124, 0xF, 0xF, true); // row_ror:4
    v += __builtin_bit_cast(float, x);
    x = __builtin_amdgcn_update_dpp(0, __builtin_bit_cast(int, v), 0x128, 0xF, 0xF, true); // row_ror:8
    v += __builtin_bit_cast(float, x);
    v += __builtin_bit_cast(float, __builtin_amdgcn_ds_swizzle(__builtin_bit_cast(int, v), 0x401F)); // xor 16
    return v;
}

// ---------------- setup: cnt=0 | Wc,bc | Wb (all independent) ----------------
__global__ __launch_bounds__(256) void k_setup(const float* __restrict__ W_ep,
    const float* __restrict__ b_ep, const float* __restrict__ W_e,
    const float* __restrict__ Wl, const float* __restrict__ Wr,
    float* __restrict__ Wc, float* __restrict__ bc,
    unsigned short* __restrict__ Wb, int* __restrict__ cnt, int n) {
    const int NB_W = (GBN / 32) * (DIN / 32);       // 64
    int b = blockIdx.x;
    if (b < NB_W) {
        __shared__ unsigned short tile[32][33];
        int bx = b & 7, by = b >> 3;                // bx: col tile, by: k tile
        int tx = threadIdx.x & 31, ty = threadIdx.x >> 5;
        int c0 = bx * 32, k0 = by * 32;
#pragma unroll
        for (int i = 0; i < 4; ++i) {
            int k = k0 + ty + i * 8;
            int col = c0 + tx;
            float v = (col < HC) ? Wl[(size_t)k * HC + col] : Wr[(size_t)k * HC + (col - HC)];
            tile[ty + i * 8][tx] = f2bf(v);
        }
        __syncthreads();
#pragma unroll
        for (int i = 0; i < 4; ++i) {
            int col = c0 + ty + i * 8;
            int k = k0 + tx;
            Wb[(size_t)col * DIN + k] = tile[tx][ty + i * 8];
        }
    } else if (b < NB_W + 9) {
        int tid = (b - NB_W) * 256 + threadIdx.x;
        if (tid < EDIM * HC) {
            int k = tid >> 7, j = tid & 127;
            float s = 0.f;
            for (int d = 0; d < DIN; ++d) s += W_ep[k * DIN + d] * W_e[d * HC + j];
            Wc[tid] = s;
        } else if (tid < EDIM * HC + HC) {
            int j = tid - EDIM * HC;
            float s = 0.f;
            for (int d = 0; d < DIN; ++d) s += b_ep[d] * W_e[d * HC + j];
            bc[j] = s;
        }
    } else {
        int i = (b - NB_W - 9) * 256 + threadIdx.x;
        if (i < n) cnt[i] = 0;
    }
}

// ---------------- fused: MFMA GEMM (first) + bucket scatter -------------------
// blocks [0, MMB): GEMM tile m0; blocks [MMB, MMB+SCB): scatter edges.
// GEMM blocks all become resident immediately; scatter fills spare slots.
__global__ __launch_bounds__(256) void k_mmsc(const float* __restrict__ x,
    const unsigned short* __restrict__ Wb,
    const float* __restrict__ bl, const float* __restrict__ br,
    unsigned* __restrict__ xlq, float* __restrict__ xrp,
    const int* __restrict__ ei, int* __restrict__ cnt,
    intx2* __restrict__ buckets, int M, int E, int MMB) {
    __shared__ unsigned short As[GBM * LDS_STRIDE];
    __shared__ unsigned short Bs[GBN * LDS_STRIDE];

    int t = threadIdx.x;
    if ((int)blockIdx.x >= MMB) {
        int e = (blockIdx.x - MMB) * 256 + t;
        if (e < E) {
            int dst = ei[E + e];
            int pos = atomicAdd(&cnt[dst], 1);
            if (pos < BSTRIDE) {
                intx2 se; se.x = ei[e]; se.y = e;
                buckets[(size_t)dst * BSTRIDE + pos] = se;
            }
        }
        return;
    }

    int wid = t >> 6, lane = t & 63;
    int m0 = blockIdx.x * GBM;

    floatx4 acc[4][4];
#pragma unroll
    for (int i = 0; i < 4; ++i)
#pragma unroll
        for (int j = 0; j < 4; ++j) acc[i][j] = (floatx4){0.f, 0.f, 0.f, 0.f};

    int row_l = lane & 15, kg = (lane >> 4) * 8;

    for (int kb = 0; kb < DIN; kb += GBK) {
        {   // stage A: 64 rows x 32 fp32 -> bf16
            int r = t >> 2, kk = (t & 3) * 8;
            int gr = m0 + r; if (gr >= M) gr = M - 1;
            const float* xp = x + (size_t)gr * DIN + kb + kk;
            floatx4 v0 = *(const floatx4*)xp;
            floatx4 v1 = *(const floatx4*)(xp + 4);
            ushort4v u0, u1;
            u0[0] = f2bf(v0[0]); u0[1] = f2bf(v0[1]); u0[2] = f2bf(v0[2]); u0[3] = f2bf(v0[3]);
            u1[0] = f2bf(v1[0]); u1[1] = f2bf(v1[1]); u1[2] = f2bf(v1[2]); u1[3] = f2bf(v1[3]);
            *(ushort4v*)(&As[r * LDS_STRIDE + kk]) = u0;
            *(ushort4v*)(&As[r * LDS_STRIDE + kk + 4]) = u1;
        }
#pragma unroll
        for (int j = 0; j < 4; ++j) {          // stage B: 256 cols x 32 bf16
            int c = t + 256 * j;
            int col = c >> 2, kk = (c & 3) * 8;
            short8v v = *(const short8v*)(Wb + (size_t)col * DIN + kb + kk);
            *(short8v*)(&Bs[col * LDS_STRIDE + kk]) = v;
        }
        __syncthreads();

        short8v a[4], b[4];
#pragma unroll
        for (int i = 0; i < 4; ++i)
            a[i] = *(short8v*)(&As[(i * 16 + row_l) * LDS_STRIDE + kg]);
#pragma unroll
        for (int j = 0; j < 4; ++j)
            b[j] = *(short8v*)(&Bs[(wid * 64 + j * 16 + row_l) * LDS_STRIDE + kg]);
#pragma unroll
        for (int i = 0; i < 4; ++i)
#pragma unroll
            for (int j = 0; j < 4; ++j)
                acc[i][j] = __builtin_amdgcn_mfma_f32_16x16x32_bf16(a[i], b[j], acc[i][j], 0, 0, 0);
        __syncthreads();
    }

    int colf = lane & 15, rq = (lane >> 4) * 4;
    if (wid < 2) {
        // xl half: packed bf16x2, one u32 per (row, l) -> coalesced
#pragma unroll
        for (int j = 0; j < 2; ++j) {
            int col = wid * 64 + j * 16 + colf;
            float bs_lo = bl[col], bs_hi = bl[col + 32];
            int l = wid * 32 + j * 16 + colf;
#pragma unroll
            for (int i = 0; i < 4; ++i) {
#pragma unroll
                for (int q = 0; q < 4; ++q) {
                    int row = m0 + i * 16 + rq + q;
                    if (row < M) {
                        unsigned lo = f2bf(acc[i][j][q] + bs_lo);
                        unsigned hi = f2bf(acc[i][j + 2][q] + bs_hi);
                        xlq[(size_t)row * 64 + l] = lo | (hi << 16);
                    }
                }
            }
        }
    } else {
        // xr half: full float2 per (row, l) -> no write amplification
#pragma unroll
        for (int j = 0; j < 2; ++j) {
            int col = wid * 64 + j * 16 + colf;
            int pc = col - HC;                    // 0..31 (wid=2) / 64..95 (wid=3)
            float bs_lo = br[pc], bs_hi = br[pc + 32];
            int l = (pc >> 6) * 32 + (pc & 31);
#pragma unroll
            for (int i = 0; i < 4; ++i) {
#pragma unroll
                for (int q = 0; q < 4; ++q) {
                    int row = m0 + i * 16 + rq + q;
                    if (row < M) {
                        floatx2 v;
                        v.x = acc[i][j][q] + bs_lo;
                        v.y = acc[i][j + 2][q] + bs_hi;
                        *(floatx2*)(xrp + ((size_t)row * 64 + l) * 2) = v;
                    }
                }
            }
        }
    }
}

// ---------------- fused per-node attention + aggregation ----------------------
// Best measured structure: 128 threads = 2 waves = 2 nodes; half-wave per head;
// lane owns 2 ch; packed-bf16 xl gather; unroll-4.
__global__ __launch_bounds__(128, 4) void k_node(const unsigned* __restrict__ xlq,
    const float* __restrict__ xrp, const float* __restrict__ Wc,
    const float* __restrict__ bc, const float* __restrict__ att,
    const float* __restrict__ bias, const int* __restrict__ cnt,
    const intx2* __restrict__ buckets,
    const float* __restrict__ edge_attr, float* __restrict__ out, int n) {
    int wid = __builtin_amdgcn_readfirstlane(threadIdx.x >> 6);
    int lane = threadIdx.x & 63;
    int node = blockIdx.x * 2 + wid;
    if (node >= n) return;
    int g = lane >> 5;
    int ch_a = g * 64 + (lane & 31);
    int ch_b = ch_a + 32;

    floatx2 wc2[EDIM];
#pragma unroll
    for (int k = 0; k < EDIM; ++k) {
        wc2[k].x = Wc[k * HC + ch_a];
        wc2[k].y = Wc[k * HC + ch_b];
    }
    const float L2E = 1.44269504f;
    floatx2 att2; att2.x = att[ch_a] * L2E; att2.y = att[ch_b] * L2E;
    floatx2 xr2 = *(const floatx2*)(xrp + ((size_t)node * 64 + lane) * 2);
    floatx2 base2; base2.x = bc[ch_a] + xr2.x; base2.y = bc[ch_b] + xr2.y;

    int deg = cnt[node]; if (deg > BSTRIDE) deg = BSTRIDE;
    const intx2* __restrict__ bk = buckets + (size_t)node * BSTRIDE;

    // prefetch bucket entries: lane p holds entry p (deg <= 64)
    int bsrc = 0, beid = 0;
    if (lane < deg) {
        intx2 se = bk[lane];
        bsrc = se.x; beid = se.y;
    }

    float D0 = 0.f, D1 = 0.f, D2 = 0.f, D3 = 0.f;
    floatx2 z; z.x = 0.f; z.y = 0.f;
    floatx2 acc0 = z, acc1 = z, acc2 = z, acc3 = z;

    for (int p = 0; p < deg; p += 4) {
        int s0 = __builtin_amdgcn_readlane(bsrc, p);
        int e0 = __builtin_amdgcn_readlane(beid, p);
        int s1 = __builtin_amdgcn_readlane(bsrc, p + 1);
        int e1 = __builtin_amdgcn_readlane(beid, p + 1);
        int s2 = __builtin_amdgcn_readlane(bsrc, p + 2);
        int e2 = __builtin_amdgcn_readlane(beid, p + 2);
        int s3 = __builtin_amdgcn_readlane(bsrc, p + 3);
        int e3 = __builtin_amdgcn_readlane(beid, p + 3);
        // all 4 gathers in flight
        unsigned v0 = xlq[(size_t)s0 * 64 + lane];
        unsigned v1 = xlq[(size_t)s1 * 64 + lane];
        unsigned v2 = xlq[(size_t)s2 * 64 + lane];
        unsigned v3 = xlq[(size_t)s3 * 64 + lane];

#define SLOT(K, vv, ee_id, Dk, acck)                                              \
        {                                                                          \
            const floatx4* __restrict__ ea = (const floatx4*)(edge_attr + (size_t)(ee_id) * EDIM); \
            floatx2 ee = base2;                                                    \
            _Pragma("unroll")                                                      \
            for (int q = 0; q < 4; ++q) {                                          \
                floatx4 av = ea[q];                                                \
                _Pragma("unroll")                                                  \
                for (int k = 0; k < 4; ++k) ee += av[k] * wc2[q * 4 + k];          \
            }                                                                      \
            floatx2 xl2;                                                           \
            xl2.x = __builtin_bit_cast(float, (vv) << 16);                         \
            xl2.y = __builtin_bit_cast(float, (vv) & 0xFFFF0000u);                 \
            floatx2 m = xl2 + ee;                                                  \
            floatx2 lr;                                                            \
            lr.x = fmaxf(m.x, 0.f) + 0.2f * fminf(m.x, 0.f);                       \
            lr.y = fmaxf(m.y, 0.f) + 0.2f * fminf(m.y, 0.f);                       \
            float sc = lr.x * att2.x + lr.y * att2.y;                              \
            sc = rsum32(sc);                                                       \
            float w = (p + (K) < deg) ? exp2f(sc) : 0.f;                           \
            Dk += w;                                                               \
            acck += w * xl2;                                                       \
        }

        SLOT(0, v0, e0, D0, acc0)
        SLOT(1, v1, e1, D1, acc1)
        SLOT(2, v2, e2, D2, acc2)
        SLOT(3, v3, e3, D3, acc3)
#undef SLOT
    }

    float D = (D0 + D1) + (D2 + D3);
    floatx2 acc = (acc0 + acc1) + (acc2 + acc3);
    float invD = (D > 0.f) ? 1.f / D : 0.f;
    out[(size_t)node * HC + ch_a] = acc.x * invD + bias[ch_a];
    out[(size_t)node * HC + ch_b] = acc.y * invD + bias[ch_b];
}

// -----------------------------------------------------------------------------
extern "C" void kernel_launch(void* const* d_in, const int* in_sizes, int n_in,
                              void* d_out, int out_size, void* d_ws, size_t ws_size,
                              hipStream_t stream) {
    const float* x    = (const float*)d_in[0];
    const int*   ei   = (const int*)d_in[1];
    const float* eatt = (const float*)d_in[2];
    const float* W_ep = (const float*)d_in[3];
    const float* b_ep = (const float*)d_in[4];
    const float* W_l  = (const float*)d_in[5];
    const float* b_l  = (const float*)d_in[6];
    const float* W_r  = (const float*)d_in[7];
    const float* b_r  = (const float*)d_in[8];
    const float* W_e  = (const float*)d_in[9];
    const float* att  = (const float*)d_in[10];
    const float* bias = (const float*)d_in[11];
    float* out = (float*)d_out;

    const int N = in_sizes[0] / DIN;
    const int E = in_sizes[1] / 2;

    char* w = (char*)d_ws;
    size_t o = 0;
    auto alloc = [&](size_t bytes) {
        o = (o + 255) & ~(size_t)255;
        void* p = w + o;
        o += bytes;
        return p;
    };
    unsigned* xlq      = (unsigned*)alloc((size_t)N * 64 * sizeof(unsigned));
    float* xrp         = (float*)alloc((size_t)N * HC * sizeof(float));
    intx2* buckets     = (intx2*)alloc((size_t)N * BSTRIDE * sizeof(intx2));
    unsigned short* Wb = (unsigned short*)alloc((size_t)GBN * DIN * sizeof(unsigned short));
    float* Wc          = (float*)alloc(EDIM * HC * sizeof(float));
    float* bc          = (float*)alloc(HC * sizeof(float));
    int*   cnt         = (int*)alloc((size_t)N * sizeof(int));

    const int NB_W = (GBN / 32) * (DIN / 32);                 // 64
    int setup_blocks = NB_W + 9 + (N + 255) / 256;
    k_setup<<<setup_blocks, 256, 0, stream>>>(W_ep, b_ep, W_e, W_l, W_r,
                                              Wc, bc, Wb, cnt, N);

    int MMB = (N + GBM - 1) / GBM;
    int SCB = (E + 255) / 256;
    k_mmsc<<<MMB + SCB, 256, 0, stream>>>(x, Wb, b_l, b_r, xlq, xrp,
                                          ei, cnt, buckets, N, E, MMB);

    k_node<<<(N + 1) / 2, 128, 0, stream>>>(xlq, xrp, Wc, bc, att, bias, cnt, buckets,
                                            eatt, out, N);
}